// Round 1
// baseline (851.723 us; speedup 1.0000x reference)
//
#include <hip/hip_runtime.h>
#include <hip/hip_bf16.h>

typedef __bf16 bf16x8 __attribute__((ext_vector_type(8)));
typedef float  f32x4  __attribute__((ext_vector_type(4)));

#define N_TOT   16384
#define K_TOT   16384
#define HALF_M  ((size_t)128 * 16384)
#define BN      64
#define BK      64
#define NSTEPS  (K_TOT / BK)   // 256

__device__ __forceinline__ unsigned short f2bf(float f) {
    __hip_bfloat16 h = __float2bfloat16(f);
    return __builtin_bit_cast(unsigned short, h);
}

// Swizzled byte offset in a tile with 128-B rows (64 bf16), 16-B granules.
// XOR of (row&7) into the granule index kills the stride-128B bank conflict
// (guide G4); remaining aliasing is 2-way == free (m136).
__device__ __forceinline__ int swz(int row, int g) {
    return row * 128 + (((g ^ (row & 7)) & 7) << 4);
}

// One-time T = concat(x0,x1) fp32 -> bf16 into workspace (linear row-major).
__global__ void cvtT_kernel(const float* __restrict__ x0,
                            const float* __restrict__ x1,
                            unsigned short* __restrict__ wsT) {
    size_t i = (size_t)blockIdx.x * blockDim.x + threadIdx.x;  // 0..524287
    size_t e = i * 8;
    const float* src = (e < HALF_M) ? (x0 + e) : (x1 + (e - HALF_M));
    float4 a = ((const float4*)src)[0];
    float4 b = ((const float4*)src)[1];
    union { unsigned short u[8]; uint4 v; } o;
    o.u[0] = f2bf(a.x); o.u[1] = f2bf(a.y); o.u[2] = f2bf(a.z); o.u[3] = f2bf(a.w);
    o.u[4] = f2bf(b.x); o.u[5] = f2bf(b.y); o.u[6] = f2bf(b.z); o.u[7] = f2bf(b.w);
    ((uint4*)wsT)[i] = o.v;
}

// GEMM: C[256 x 16384] = T(256x16384,bf16) * W^T(16384x16384,f32->bf16) + b.
// Each WG owns 64 W-rows (BN) x all 256 T-rows, loops full K.
// 16 waves: wm=wave>>2 (M quadrant of 64 rows), wn=wave&3 (16 W-rows each).
template<bool USE_WS>
__global__ __launch_bounds__(1024)
void gemm_kernel(const float* __restrict__ x0, const float* __restrict__ x1,
                 const float* __restrict__ W,  const float* __restrict__ bias,
                 const unsigned short* __restrict__ wsT,
                 float* __restrict__ out)
{
    __shared__ uint4 smem_[(2 * 32768 + 2 * 8192) / 16];   // 80 KiB
    char* const sm = (char*)smem_;
    char* const A0 = sm;                  // A tiles: 256 rows x 128 B
    char* const A1 = sm + 32768;
    char* const B0 = sm + 65536;          // B tiles: 64 rows x 128 B
    char* const B1 = sm + 65536 + 8192;

    const int tid  = threadIdx.x;
    const int lane = tid & 63;
    const int wave = tid >> 6;
    const int wm = wave >> 2;
    const int wn = wave & 3;
    const int n0 = blockIdx.x * BN;

    // staging geometry: A - thread covers 16 bf16 (32 B) of one row
    const int ra = tid >> 2;              // A row 0..255
    const int pa = tid & 3;               // which 32-B chunk of the 128-B row
    // B - thread covers 4 f32 of one W row
    const int rbs = tid >> 4;             // B row 0..63
    const int cbs = (tid & 15) * 4;       // f32 col offset

    const float* arow_f = (ra < 128) ? (x0 + (size_t)ra * K_TOT)
                                     : (x1 + (size_t)(ra - 128) * K_TOT);
    const unsigned short* arow_w = wsT + (size_t)ra * K_TOT;
    const float* brow = W + (size_t)(n0 + rbs) * K_TOT + cbs;

    const int aw0 = swz(ra, 2 * pa);
    const int aw1 = swz(ra, 2 * pa + 1);
    const int bw  = rbs * 128 + (((((tid & 15) >> 1) ^ (rbs & 7)) & 7) << 4) + (tid & 1) * 8;

    // compute-side LDS read offsets (fragment layout: row=lane&15, k-chunk=(lane>>4)*8)
    int aoff[4][2], boff[2];
    #pragma unroll
    for (int mf = 0; mf < 4; ++mf)
        #pragma unroll
        for (int kf = 0; kf < 2; ++kf)
            aoff[mf][kf] = swz(wm * 64 + mf * 16 + (lane & 15), kf * 4 + (lane >> 4));
    #pragma unroll
    for (int kf = 0; kf < 2; ++kf)
        boff[kf] = swz(wn * 16 + (lane & 15), kf * 4 + (lane >> 4));

    f32x4 acc[4] = {};

    uint4  arw[2];
    float4 arf[4];
    float4 brg;

    auto issue = [&](int k0) {
        if constexpr (USE_WS) {
            const uint4* p = (const uint4*)(arow_w + k0 + pa * 16);
            arw[0] = p[0]; arw[1] = p[1];
        } else {
            const float4* p = (const float4*)(arow_f + k0 + pa * 16);
            arf[0] = p[0]; arf[1] = p[1]; arf[2] = p[2]; arf[3] = p[3];
        }
        brg = *(const float4*)(brow + k0);
    };

    auto stage = [&](char* Ab, char* Bb) {
        if constexpr (USE_WS) {
            *(uint4*)(Ab + aw0) = arw[0];
            *(uint4*)(Ab + aw1) = arw[1];
        } else {
            union { unsigned short u[8]; uint4 v; } t0, t1;
            const float* f = (const float*)arf;
            #pragma unroll
            for (int j = 0; j < 8; ++j) { t0.u[j] = f2bf(f[j]); t1.u[j] = f2bf(f[j + 8]); }
            *(uint4*)(Ab + aw0) = t0.v;
            *(uint4*)(Ab + aw1) = t1.v;
        }
        union { unsigned short u[4]; uint2 v; } tb;
        tb.u[0] = f2bf(brg.x); tb.u[1] = f2bf(brg.y);
        tb.u[2] = f2bf(brg.z); tb.u[3] = f2bf(brg.w);
        *(uint2*)(Bb + bw) = tb.v;
    };

    auto compute = [&](const char* Ab, const char* Bb) {
        bf16x8 bf[2];
        #pragma unroll
        for (int kf = 0; kf < 2; ++kf)
            bf[kf] = *(const bf16x8*)(Bb + boff[kf]);
        #pragma unroll
        for (int mf = 0; mf < 4; ++mf) {
            #pragma unroll
            for (int kf = 0; kf < 2; ++kf) {
                bf16x8 af = *(const bf16x8*)(Ab + aoff[mf][kf]);
                acc[mf] = __builtin_amdgcn_mfma_f32_16x16x32_bf16(af, bf[kf], acc[mf], 0, 0, 0);
            }
        }
    };

    issue(0);
    stage(A0, B0);
    __syncthreads();

    char* Ac = A0; char* Bc = B0; char* An = A1; char* Bn = B1;
    for (int kt = 0; kt < NSTEPS; ++kt) {
        const bool more = (kt + 1 < NSTEPS);
        if (more) issue((kt + 1) * BK);      // HBM loads in flight during compute
        compute(Ac, Bc);
        if (more) stage(An, Bn);             // cvt + ds_write into the other buffer
        __syncthreads();
        char* t;
        t = Ac; Ac = An; An = t;
        t = Bc; Bc = Bn; Bn = t;
    }

    // epilogue: C/D layout col=lane&15, row=(lane>>4)*4+j  (m89-verified)
    const int col = n0 + wn * 16 + (lane & 15);
    const float bv = bias[col];
    #pragma unroll
    for (int mf = 0; mf < 4; ++mf) {
        #pragma unroll
        for (int j = 0; j < 4; ++j) {
            int r = wm * 64 + mf * 16 + (lane >> 4) * 4 + j;
            float v = acc[mf][j] + bv;
            float* o = (r < 128) ? (out + (size_t)r * N_TOT + col)
                                 : (out + HALF_M + (size_t)(r - 128) * N_TOT + col);
            *o = v;
        }
    }
}

extern "C" void kernel_launch(void* const* d_in, const int* in_sizes, int n_in,
                              void* d_out, int out_size, void* d_ws, size_t ws_size,
                              hipStream_t stream) {
    const float* x0 = (const float*)d_in[0];
    const float* x1 = (const float*)d_in[1];
    const float* W  = (const float*)d_in[2];
    const float* b  = (const float*)d_in[3];
    float* out = (float*)d_out;

    const size_t wsT_bytes = (size_t)256 * 16384 * sizeof(unsigned short);  // 8.4 MB
    if (ws_size >= wsT_bytes) {
        unsigned short* wsT = (unsigned short*)d_ws;
        cvtT_kernel<<<2048, 256, 0, stream>>>(x0, x1, wsT);
        gemm_kernel<true><<<256, 1024, 0, stream>>>(x0, x1, W, b, wsT, out);
    } else {
        gemm_kernel<false><<<256, 1024, 0, stream>>>(x0, x1, W, b, nullptr, out);
    }
}

// Round 2
// 304.739 us; speedup vs baseline: 2.7949x; 2.7949x over previous
//
#include <hip/hip_runtime.h>
#include <hip/hip_bf16.h>

typedef __bf16 bf16x8 __attribute__((ext_vector_type(8)));
typedef float  f32x4  __attribute__((ext_vector_type(4)));

#define N_TOT   16384
#define K_TOT   16384
#define HALF_M  ((size_t)128 * 16384)
#define BN      64
#define BK      64
#define NSTEPS  (K_TOT / BK)   // 256

__device__ __forceinline__ unsigned short f2bf(float f) {
    __hip_bfloat16 h = __float2bfloat16(f);
    return __builtin_bit_cast(unsigned short, h);
}

// Swizzled byte offset: 128-B rows, 16-B granules, XOR row&7 into granule idx.
__device__ __forceinline__ int swz(int row, int g) {
    return row * 128 + (((g ^ (row & 7)) & 7) << 4);
}

// One-time T = concat(x0,x1) fp32 -> bf16 into workspace (linear row-major).
__global__ void cvtT_kernel(const float* __restrict__ x0,
                            const float* __restrict__ x1,
                            unsigned short* __restrict__ wsT) {
    size_t i = (size_t)blockIdx.x * blockDim.x + threadIdx.x;  // 0..524287
    size_t e = i * 8;
    const float* src = (e < HALF_M) ? (x0 + e) : (x1 + (e - HALF_M));
    float4 a = ((const float4*)src)[0];
    float4 b = ((const float4*)src)[1];
    union { unsigned short u[8]; uint4 v; } o;
    o.u[0] = f2bf(a.x); o.u[1] = f2bf(a.y); o.u[2] = f2bf(a.z); o.u[3] = f2bf(a.w);
    o.u[4] = f2bf(b.x); o.u[5] = f2bf(b.y); o.u[6] = f2bf(b.z); o.u[7] = f2bf(b.w);
    ((uint4*)wsT)[i] = o.v;
}

// ---- macros: fully static, no lambdas, no runtime buffer indices ----

// Issue global loads for step k0 (element offset along K) into register set S.
#define ISSUE(S, k0) do {                                                     \
    if constexpr (USE_WS) {                                                   \
        const uint4* _p = (const uint4*)(arow_w + (k0));                      \
        w##S##_0 = _p[0]; w##S##_1 = _p[1];                                   \
    } else {                                                                  \
        const float4* _p = (const float4*)(arow_f + (k0));                    \
        f##S##_0 = _p[0]; f##S##_1 = _p[1]; f##S##_2 = _p[2]; f##S##_3 = _p[3];\
    }                                                                         \
    wb##S = *(const float4*)(brow + (k0));                                    \
} while (0)

// Convert (if needed) + ds_write register set S into LDS tiles Ab/Bb.
#define STAGE(S, Ab, Bb) do {                                                 \
    if constexpr (USE_WS) {                                                   \
        *(uint4*)((Ab) + aw0) = w##S##_0;                                     \
        *(uint4*)((Ab) + aw1) = w##S##_1;                                     \
    } else {                                                                  \
        union { unsigned short u[8]; uint4 v; } _t0, _t1;                     \
        _t0.u[0]=f2bf(f##S##_0.x); _t0.u[1]=f2bf(f##S##_0.y);                 \
        _t0.u[2]=f2bf(f##S##_0.z); _t0.u[3]=f2bf(f##S##_0.w);                 \
        _t0.u[4]=f2bf(f##S##_1.x); _t0.u[5]=f2bf(f##S##_1.y);                 \
        _t0.u[6]=f2bf(f##S##_1.z); _t0.u[7]=f2bf(f##S##_1.w);                 \
        _t1.u[0]=f2bf(f##S##_2.x); _t1.u[1]=f2bf(f##S##_2.y);                 \
        _t1.u[2]=f2bf(f##S##_2.z); _t1.u[3]=f2bf(f##S##_2.w);                 \
        _t1.u[4]=f2bf(f##S##_3.x); _t1.u[5]=f2bf(f##S##_3.y);                 \
        _t1.u[6]=f2bf(f##S##_3.z); _t1.u[7]=f2bf(f##S##_3.w);                 \
        *(uint4*)((Ab) + aw0) = _t0.v;                                        \
        *(uint4*)((Ab) + aw1) = _t1.v;                                        \
    }                                                                         \
    union { unsigned short u[4]; uint2 v; } _tb;                              \
    _tb.u[0]=f2bf(wb##S.x); _tb.u[1]=f2bf(wb##S.y);                           \
    _tb.u[2]=f2bf(wb##S.z); _tb.u[3]=f2bf(wb##S.w);                           \
    *(uint2*)((Bb) + bw) = _tb.v;                                             \
} while (0)

#define COMPUTE(Ab, Bb) do {                                                  \
    bf16x8 _bf0 = *(const bf16x8*)((Bb) + boff0);                             \
    bf16x8 _bf1 = *(const bf16x8*)((Bb) + boff1);                             \
    bf16x8 _a;                                                                \
    _a = *(const bf16x8*)((Ab) + aoff00);                                     \
    acc0 = __builtin_amdgcn_mfma_f32_16x16x32_bf16(_a, _bf0, acc0, 0, 0, 0);  \
    _a = *(const bf16x8*)((Ab) + aoff01);                                     \
    acc0 = __builtin_amdgcn_mfma_f32_16x16x32_bf16(_a, _bf1, acc0, 0, 0, 0);  \
    _a = *(const bf16x8*)((Ab) + aoff10);                                     \
    acc1 = __builtin_amdgcn_mfma_f32_16x16x32_bf16(_a, _bf0, acc1, 0, 0, 0);  \
    _a = *(const bf16x8*)((Ab) + aoff11);                                     \
    acc1 = __builtin_amdgcn_mfma_f32_16x16x32_bf16(_a, _bf1, acc1, 0, 0, 0);  \
    _a = *(const bf16x8*)((Ab) + aoff20);                                     \
    acc2 = __builtin_amdgcn_mfma_f32_16x16x32_bf16(_a, _bf0, acc2, 0, 0, 0);  \
    _a = *(const bf16x8*)((Ab) + aoff21);                                     \
    acc2 = __builtin_amdgcn_mfma_f32_16x16x32_bf16(_a, _bf1, acc2, 0, 0, 0);  \
    _a = *(const bf16x8*)((Ab) + aoff30);                                     \
    acc3 = __builtin_amdgcn_mfma_f32_16x16x32_bf16(_a, _bf0, acc3, 0, 0, 0);  \
    _a = *(const bf16x8*)((Ab) + aoff31);                                     \
    acc3 = __builtin_amdgcn_mfma_f32_16x16x32_bf16(_a, _bf1, acc3, 0, 0, 0);  \
} while (0)

// raw barrier: wait own LDS ops, barrier, pin scheduler. VMEM (wave-private
// prefetch regs) deliberately NOT drained -> loads stay in flight.
#define SYNC do {                                                             \
    asm volatile("s_waitcnt lgkmcnt(0)" ::: "memory");                        \
    __builtin_amdgcn_s_barrier();                                             \
    __builtin_amdgcn_sched_barrier(0);                                        \
} while (0)

// GEMM: C[256 x 16384] = T(256x16384,bf16) * W^T(16384x16384,f32->bf16) + b.
// grid 256 (one BN=64 column strip each), 1024 threads = 16 waves (4M x 4N).
template<bool USE_WS>
__global__ __launch_bounds__(1024)
void gemm_kernel(const float* __restrict__ x0, const float* __restrict__ x1,
                 const float* __restrict__ W,  const float* __restrict__ bias,
                 const unsigned short* __restrict__ wsT,
                 float* __restrict__ out)
{
    __shared__ uint4 smem_[(2 * 32768 + 2 * 8192) / 16];   // 80 KiB
    char* const sm = (char*)smem_;
    char* const A0 = sm;                  // A tiles: 256 rows x 128 B
    char* const A1 = sm + 32768;
    char* const B0 = sm + 65536;          // B tiles: 64 rows x 128 B
    char* const B1 = sm + 65536 + 8192;

    const int tid  = threadIdx.x;
    const int lane = tid & 63;
    const int wave = tid >> 6;
    const int wm = wave >> 2;
    const int wn = wave & 3;
    const int n0 = blockIdx.x * BN;

    // staging geometry
    const int ra  = tid >> 2;             // A row 0..255
    const int pa  = tid & 3;              // 32-B chunk of the 128-B row
    const int rbs = tid >> 4;             // B row 0..63
    const int cbs = (tid & 15) * 4;       // f32 col offset

    const unsigned short* arow_w = wsT + (size_t)ra * K_TOT + pa * 16;
    const float* arow_f = ((ra < 128) ? (x0 + (size_t)ra * K_TOT)
                                      : (x1 + (size_t)(ra - 128) * K_TOT)) + pa * 16;
    const float* brow = W + (size_t)(n0 + rbs) * K_TOT + cbs;

    const int aw0 = swz(ra, 2 * pa);
    const int aw1 = swz(ra, 2 * pa + 1);
    const int bw  = rbs * 128 + (((((tid & 15) >> 1) ^ (rbs & 7)) & 7) << 4) + (tid & 1) * 8;

    // compute-side LDS read offsets
    const int aoff00 = swz(wm * 64 +  0 + (lane & 15), 0 + (lane >> 4));
    const int aoff01 = swz(wm * 64 +  0 + (lane & 15), 4 + (lane >> 4));
    const int aoff10 = swz(wm * 64 + 16 + (lane & 15), 0 + (lane >> 4));
    const int aoff11 = swz(wm * 64 + 16 + (lane & 15), 4 + (lane >> 4));
    const int aoff20 = swz(wm * 64 + 32 + (lane & 15), 0 + (lane >> 4));
    const int aoff21 = swz(wm * 64 + 32 + (lane & 15), 4 + (lane >> 4));
    const int aoff30 = swz(wm * 64 + 48 + (lane & 15), 0 + (lane >> 4));
    const int aoff31 = swz(wm * 64 + 48 + (lane & 15), 4 + (lane >> 4));
    const int boff0  = swz(wn * 16 + (lane & 15), 0 + (lane >> 4));
    const int boff1  = swz(wn * 16 + (lane & 15), 4 + (lane >> 4));

    f32x4 acc0 = {0.f,0.f,0.f,0.f}, acc1 = {0.f,0.f,0.f,0.f};
    f32x4 acc2 = {0.f,0.f,0.f,0.f}, acc3 = {0.f,0.f,0.f,0.f};

    // two named register sets (even / odd K-step) — static, spill-proof
    uint4  w0_0, w0_1, w1_0, w1_1;
    float4 f0_0, f0_1, f0_2, f0_3, f1_0, f1_1, f1_2, f1_3;
    float4 wb0, wb1;

    ISSUE(0, 0);
    ISSUE(1, BK);
    STAGE(0, A0, B0);                     // compiler waits vmcnt for set 0 only
    SYNC;

    for (int kt = 0; kt < NSTEPS; kt += 2) {
        // phase A: compute even buf, stage odd step, prefetch kt+2 (even set)
        if (kt + 2 < NSTEPS) ISSUE(0, (kt + 2) * BK);
        COMPUTE(A0, B0);
        STAGE(1, A1, B1);                 // auto s_waitcnt vmcnt(3): set1 only
        SYNC;
        // phase B: compute odd buf, stage kt+2, prefetch kt+3 (odd set)
        if (kt + 3 < NSTEPS) ISSUE(1, (kt + 3) * BK);
        COMPUTE(A1, B1);
        if (kt + 2 < NSTEPS) STAGE(0, A0, B0);
        SYNC;
    }

    // epilogue: C/D layout col=lane&15, row=(lane>>4)*4+j
    const int col = n0 + wn * 16 + (lane & 15);
    const float bv = bias[col];
    #pragma unroll
    for (int mf = 0; mf < 4; ++mf) {
        const f32x4 a = (mf == 0) ? acc0 : (mf == 1) ? acc1 : (mf == 2) ? acc2 : acc3;
        #pragma unroll
        for (int j = 0; j < 4; ++j) {
            int r = wm * 64 + mf * 16 + (lane >> 4) * 4 + j;
            float v = a[j] + bv;
            float* o = (r < 128) ? (out + (size_t)r * N_TOT + col)
                                 : (out + HALF_M + (size_t)(r - 128) * N_TOT + col);
            *o = v;
        }
    }
}

extern "C" void kernel_launch(void* const* d_in, const int* in_sizes, int n_in,
                              void* d_out, int out_size, void* d_ws, size_t ws_size,
                              hipStream_t stream) {
    const float* x0 = (const float*)d_in[0];
    const float* x1 = (const float*)d_in[1];
    const float* W  = (const float*)d_in[2];
    const float* b  = (const float*)d_in[3];
    float* out = (float*)d_out;

    const size_t wsT_bytes = (size_t)256 * 16384 * sizeof(unsigned short);  // 8.4 MB
    if (ws_size >= wsT_bytes) {
        unsigned short* wsT = (unsigned short*)d_ws;
        cvtT_kernel<<<2048, 256, 0, stream>>>(x0, x1, wsT);
        gemm_kernel<true><<<256, 1024, 0, stream>>>(x0, x1, W, b, wsT, out);
    } else {
        gemm_kernel<false><<<256, 1024, 0, stream>>>(x0, x1, W, b, nullptr, out);
    }
}